// Round 5
// baseline (305.343 us; speedup 1.0000x reference)
//
#include <hip/hip_runtime.h>
#include <cstdint>

// Problem constants (from reference)
#define BB 32
#define TV 8192
#define KK 64
#define TS 128
#define MARGIN_F 0.1f
#define LAMBDA_F 0.5f

static constexpr int KSTR = BB * TV;     // pred_intervened stride per k (floats)
static constexpr int GPB = TV / 32;      // 256 half-groups (32 rows) per batch
static constexpr int NG = BB * GPB;      // 8192 half-groups total

// Workspace layout (bytes):
//   acc   @ 0      : 1 float
//   len   @ 64     : 32 ints (valid count per b)
//   wsV   @ 4096   : u32[8192]      bit r = valid(row 32g+r)          (32 KB)
//   wsA   @ 65536  : u32[8192][64]  [g][k] bit r = aligned&valid      (2 MB)
static constexpr size_t ACC_OFF = 0;
static constexpr size_t LEN_OFF = 64;
static constexpr size_t WSV_OFF = 4096;
static constexpr size_t WSA_OFF = 65536;

// ---------------------------------------------------------------------------
// Pack: wave = one 32-row half-group. ZERO LDS, low VGPR -> 8 blocks/CU, and
// grid 2048 fills it (2x R4's residency). Coalesced int4 gt stream (1 KB per
// wave-load = 2 rows); ballot->row mapping verbatim from the absmax-0.0
// kernels (row 2ch from ballot bit c>>2, row 2ch+1 from bit 32+(c>>2)); lane
// k accumulates its own u32 plane. Invalid half-groups skip the gt stream.
// ---------------------------------------------------------------------------
__global__ __launch_bounds__(256) void pack_kernel(
    const int* __restrict__ gt, const int* __restrict__ mv,
    const int* __restrict__ idx,
    unsigned int* __restrict__ wsA, unsigned int* __restrict__ wsV,
    int* __restrict__ len) {
  const int lane = threadIdx.x & 63;
  const int g = blockIdx.x * 4 + (threadIdx.x >> 6);   // half-group id 0..8191
  const int r0 = g * 32;
  const int b = g >> 8;                                // GPB = 256
  const int c = idx[lane];                             // lane == k
  const int csel = c & 3, csh = c >> 2;

  // validity of rows r0..r0+31 (lanes 32..63 duplicate -> take low 32 bits)
  const unsigned int V = (unsigned int)__ballot(mv[r0 + (lane & 31)] != 0);
  if (lane == 0) {
    wsV[g] = V;
    if (V) atomicAdd(&len[b], __popc(V));
  }

  unsigned int plane = 0u;
  if (V != 0u) {
    const int4* rowp = (const int4*)(gt + (size_t)r0 * TS);
#pragma unroll 4
    for (int ch = 0; ch < 16; ++ch) {
      int4 v = rowp[ch * 64 + lane];                   // 2 full rows per load
      unsigned long long b0 = __ballot(v.x > 0);
      unsigned long long b1 = __ballot(v.y > 0);
      unsigned long long b2 = __ballot(v.z > 0);
      unsigned long long b3 = __ballot(v.w > 0);
      unsigned long long sel =
          (csel == 0) ? b0 : (csel == 1) ? b1 : (csel == 2) ? b2 : b3;
      const unsigned int raw0 = (unsigned int)((sel >> csh) & 1ull);        // row 2ch
      const unsigned int raw1 = (unsigned int)((sel >> (32 + csh)) & 1ull); // row 2ch+1
      plane |= (raw0 << (2 * ch)) | (raw1 << (2 * ch + 1));
    }
    plane &= V;                                        // aligned requires valid
  }
  wsA[(size_t)g * 64 + lane] = plane;                  // coalesced 256 B/wave
}

// ---------------------------------------------------------------------------
// Main: one block per (k,b), 2048 blocks, 2 KB LDS -> 8 blocks/CU. Grid-
// stride over t with 2x float4 loads (po is 1 MB -> L2-resident). Masks from
// LDS u32 words (same-address broadcast within 8-lane groups: conflict-free).
// No cross-lane ops until ONE per-block epilogue; one atomicAdd per block.
// ---------------------------------------------------------------------------
__global__ __launch_bounds__(256) void main_kernel(
    const float* __restrict__ po, const float* __restrict__ pi,
    const unsigned int* __restrict__ wsA, const unsigned int* __restrict__ wsV,
    const int* __restrict__ len, float* __restrict__ acc) {
  const int k = blockIdx.x & (KK - 1);
  const int b = blockIdx.x >> 6;
  const int tid = threadIdx.x;

  __shared__ unsigned int sA[GPB];   // my k's plane words for this b
  __shared__ unsigned int sV[GPB];
  sA[tid] = wsA[(size_t)(b * GPB + tid) * 64 + k];
  sV[tid] = wsV[b * GPB + tid];
  __syncthreads();

  const float* pob = po + (size_t)b * TV;
  const float* pik = pi + (size_t)k * KSTR + (size_t)b * TV;
  const int L = len[b];                        // prefix length, >= TV/2
  const int Tlim = (L + 1023) & ~1023;         // granularity 256 thr * 4 elem

  float sa = 0.f, sv = 0.f;
  int ca = 0;
  for (int t0 = tid * 4; t0 < Tlim; t0 += 1024) {
    const float4 xo = *(const float4*)(pob + t0);
    const float4 xi = *(const float4*)(pik + t0);
    const unsigned ab = (sA[t0 >> 5] >> (t0 & 31)) & 15u;
    const unsigned vb = (sV[t0 >> 5] >> (t0 & 31)) & 15u;
    {
      const float e = fabsf(__fdividef(1.f, 1.f + __expf(-xo.x)) -
                            __fdividef(1.f, 1.f + __expf(-xi.x)));
      if (ab & 1u) sa += e;
      if (vb & 1u) sv += e;
    }
    {
      const float e = fabsf(__fdividef(1.f, 1.f + __expf(-xo.y)) -
                            __fdividef(1.f, 1.f + __expf(-xi.y)));
      if (ab & 2u) sa += e;
      if (vb & 2u) sv += e;
    }
    {
      const float e = fabsf(__fdividef(1.f, 1.f + __expf(-xo.z)) -
                            __fdividef(1.f, 1.f + __expf(-xi.z)));
      if (ab & 4u) sa += e;
      if (vb & 4u) sv += e;
    }
    {
      const float e = fabsf(__fdividef(1.f, 1.f + __expf(-xo.w)) -
                            __fdividef(1.f, 1.f + __expf(-xi.w)));
      if (ab & 8u) sa += e;
      if (vb & 8u) sv += e;
    }
    ca += __popc(ab);
  }

  // epilogue: one block reduction, one atomic
  float fca = (float)ca;
#pragma unroll
  for (int off = 32; off > 0; off >>= 1) {
    sa += __shfl_down(sa, off);
    sv += __shfl_down(sv, off);
    fca += __shfl_down(fca, off);
  }
  __shared__ float p0[4], p1[4], p2[4];
  const int w = tid >> 6;
  if ((tid & 63) == 0) { p0[w] = sa; p1[w] = sv; p2[w] = fca; }
  __syncthreads();
  if (tid == 0) {
    const float SA = p0[0] + p0[1] + p0[2] + p0[3];
    const float SV = p1[0] + p1[1] + p1[2] + p1[3];
    const float CA = p2[0] + p2[1] + p2[2] + p2[3];
    const float CN = (float)L - CA;            // aligned is subset of valid
    float pp = 0.f;
    if (CA > 0.f && CN > 0.f) {
      const float d = MARGIN_F - (SA / CA - (SV - SA) / CN);
      pp = d > 0.f ? d : 0.f;
    }
    atomicAdd(acc, pp);
  }
}

__global__ void fin_kernel(const float* __restrict__ acc, float* __restrict__ out) {
  const float ac = acc[0] * (1.0f / (float)(KK * BB));
  out[0] = ac;
  out[1] = ac * LAMBDA_F;
}

extern "C" void kernel_launch(void* const* d_in, const int* in_sizes, int n_in,
                              void* d_out, int out_size, void* d_ws, size_t ws_size,
                              hipStream_t stream) {
  const float* pred_orig = (const float*)d_in[0];   // [B,TV] fp32
  const float* pred_int  = (const float*)d_in[1];   // [K,B,TV] fp32
  const int*   idx       = (const int*)d_in[2];     // [K] int32
  const int*   gt        = (const int*)d_in[3];     // [B,TV,TS] int32
  const int*   mv        = (const int*)d_in[4];     // [B,TV] int32
  float* out = (float*)d_out;

  char* ws = (char*)d_ws;
  float* acc = (float*)(ws + ACC_OFF);
  int* len = (int*)(ws + LEN_OFF);
  unsigned int* wsV = (unsigned int*)(ws + WSV_OFF);
  unsigned int* wsA = (unsigned int*)(ws + WSA_OFF);

  hipMemsetAsync(ws, 0, 192, stream);   // acc + len (ws re-poisoned each call)
  pack_kernel<<<NG / 4, 256, 0, stream>>>(gt, mv, idx, wsA, wsV, len);
  main_kernel<<<BB * KK, 256, 0, stream>>>(pred_orig, pred_int, wsA, wsV, len, acc);
  fin_kernel<<<1, 1, 0, stream>>>(acc, out);
}

// Round 6
// 264.678 us; speedup vs baseline: 1.1536x; 1.1536x over previous
//
#include <hip/hip_runtime.h>
#include <cstdint>

// Problem constants (from reference)
#define BB 32
#define TV 8192
#define KK 64
#define TS 128
#define MARGIN_F 0.1f
#define LAMBDA_F 0.5f

#define TT 256                                 // t-tile per block
static constexpr int KSTR = BB * TV;           // pred_intervened stride per k
static constexpr int NTILE = TV / TT;          // 32 tiles per batch

// Workspace (floats, contiguous so one memset covers):
//   gsa[KK*BB] : sum(eff*aligned) per (k,b)
//   gsv[KK*BB] : sum(eff*valid)   per (k,b)
//   gca[KK*BB] : count(aligned)   per (k,b)
//   len[BB]    : count(valid)     per b (int)
// en = (gsv-gsa)/(len-gca)  (aligned is a subset of valid).

// ---------------------------------------------------------------------------
// ONE fused kernel (R4 structure, MLP-fixed). Block = (b, 256-t tile).
// Phase A: ballot-transpose pack of gt (bit logic verbatim from the absmax-0.0
//          rounds) with an EXPLICIT 4-deep load pipeline: 4 independent int4
//          row-pair loads issued in program order before any ballot touches
//          them, next batch prefetched while processing (R5 showed the
//          compiler alone keeps only 1 load in flight -> VGPR 12, 610 GB/s).
// Phase B: wave w owns k in [16w,16w+16), batched by 4: 4 independent float4
//          pi loads per batch. Per-k wave pre-reduction = 3 shfl_down steps
//          (64->8 lanes, 6 shuffles/k) then LDS slab [64][9] -> LDS total
//          7.6 KB (was 36.9).
// Epilogue: tid<64 reduces 8+8 floats per k, 3 coalesced atomics.
// ---------------------------------------------------------------------------
__global__ __launch_bounds__(256, 4) void fused_kernel(
    const float* __restrict__ po, const float* __restrict__ pi,
    const int* __restrict__ idx, const int* __restrict__ gt,
    const int* __restrict__ mv,
    float* __restrict__ gsa, float* __restrict__ gsv,
    float* __restrict__ gca, int* __restrict__ len) {
  const int tid = threadIdx.x;
  const int lane = tid & 63;
  const int w = tid >> 6;
  const int tile = blockIdx.x & (NTILE - 1);
  const int b = blockIdx.x >> 5;               // log2(NTILE)=5
  const int t0 = tile * TT;

  __shared__ unsigned long long planes[4][65]; // [group][k], +1 pad
  __shared__ unsigned long long sVg[4];        // valid bits per group
  __shared__ float so[TT];                     // sigmoid(pred_orig) tile
  __shared__ float saL[KK][9];                 // per-(k, lanegroup) partials
  __shared__ float svL[KK][9];

  // ---- Phase A ----
  const int r0 = b * TV + t0 + w * 64;         // global row of this wave's group
  const unsigned long long V = __ballot(mv[r0 + lane] != 0);
  if (lane == 0) {
    sVg[w] = V;
    if (V) atomicAdd(&len[b], __popcll(V));
  }
  so[tid] = __fdividef(1.f, 1.f + __expf(-po[b * TV + t0 + tid]));

  const int c = idx[lane];                     // lane extracts column for k=lane
  const int csel = c & 3, csh = c >> 2;
  unsigned long long plane = 0ull;

  if (V != 0ull) {
    const int4* rowp = (const int4*)(gt + (size_t)r0 * TS) + lane;

    // process one int4 (2 rows: 2ch and 2ch+1) -> 2 plane bits
    auto procA = [&](int4 v, int ch) {
      unsigned long long b0 = __ballot(v.x > 0);
      unsigned long long b1 = __ballot(v.y > 0);
      unsigned long long b2 = __ballot(v.z > 0);
      unsigned long long b3 = __ballot(v.w > 0);
      unsigned long long sel =
          (csel == 0) ? b0 : (csel == 1) ? b1 : (csel == 2) ? b2 : b3;
      const unsigned long long raw0 = (sel >> csh) & 1ull;          // row 2ch
      const unsigned long long raw1 = (sel >> (32 + csh)) & 1ull;   // row 2ch+1
      plane |= (raw0 << (2 * ch)) | (raw1 << (2 * ch + 1));
    };

    // 4-deep pipeline over 8 batches of 4 loads (32 row-pairs = 64 rows)
    int4 v0 = rowp[0 * 64], v1 = rowp[1 * 64], v2 = rowp[2 * 64], v3 = rowp[3 * 64];
#pragma unroll
    for (int ch = 0; ch < 32; ch += 4) {
      int4 n0 = v0, n1 = v1, n2 = v2, n3 = v3;
      if (ch + 4 < 32) {
        n0 = rowp[(ch + 4) * 64];
        n1 = rowp[(ch + 5) * 64];
        n2 = rowp[(ch + 6) * 64];
        n3 = rowp[(ch + 7) * 64];
      }
      procA(v0, ch);
      procA(v1, ch + 1);
      procA(v2, ch + 2);
      procA(v3, ch + 3);
      v0 = n0; v1 = n1; v2 = n2; v3 = n3;
    }
    plane &= V;                                // aligned requires valid
  }
  planes[w][lane] = plane;
  __syncthreads();

  // fully-invalid tile: nothing to accumulate
  if ((sVg[0] | sVg[1] | sVg[2] | sVg[3]) == 0ull) return;

  // ---- Phase B ----  lane handles t_local = lane*4 .. lane*4+3
  const int g = lane >> 4;                     // (lane*4)>>6
  const int sh4 = (lane & 15) * 4;             // (lane*4)&63
  const unsigned vb4 = (unsigned)((sVg[g] >> sh4) & 15ull);
  const float4 so4 = *(const float4*)&so[lane * 4];
  const float* pib = pi + (size_t)b * TV + t0 + lane * 4;

  auto procB = [&](float4 xi, int k) {
    const unsigned ab4 = (unsigned)((planes[g][k] >> sh4) & 15ull);
    float sa = 0.f, sv = 0.f;
    {
      const float e = fabsf(so4.x - __fdividef(1.f, 1.f + __expf(-xi.x)));
      if (ab4 & 1u) sa += e;
      if (vb4 & 1u) sv += e;
    }
    {
      const float e = fabsf(so4.y - __fdividef(1.f, 1.f + __expf(-xi.y)));
      if (ab4 & 2u) sa += e;
      if (vb4 & 2u) sv += e;
    }
    {
      const float e = fabsf(so4.z - __fdividef(1.f, 1.f + __expf(-xi.z)));
      if (ab4 & 4u) sa += e;
      if (vb4 & 4u) sv += e;
    }
    {
      const float e = fabsf(so4.w - __fdividef(1.f, 1.f + __expf(-xi.w)));
      if (ab4 & 8u) sa += e;
      if (vb4 & 8u) sv += e;
    }
    // 64 -> 8 lane pre-reduction (6 cross-lane ops per k)
    sa += __shfl_down(sa, 32);
    sv += __shfl_down(sv, 32);
    sa += __shfl_down(sa, 16);
    sv += __shfl_down(sv, 16);
    sa += __shfl_down(sa, 8);
    sv += __shfl_down(sv, 8);
    if (lane < 8) { saL[k][lane] = sa; svL[k][lane] = sv; }
  };

#pragma unroll
  for (int kk = 0; kk < 16; kk += 4) {
    const int k0 = w * 16 + kk;                // this wave's exclusive k range
    const float4 x0 = *(const float4*)(pib + (size_t)(k0 + 0) * KSTR);
    const float4 x1 = *(const float4*)(pib + (size_t)(k0 + 1) * KSTR);
    const float4 x2 = *(const float4*)(pib + (size_t)(k0 + 2) * KSTR);
    const float4 x3 = *(const float4*)(pib + (size_t)(k0 + 3) * KSTR);
    procB(x0, k0 + 0);
    procB(x1, k0 + 1);
    procB(x2, k0 + 2);
    procB(x3, k0 + 3);
  }
  __syncthreads();

  // ---- Epilogue ----
  if (tid < KK) {
    const int k = tid;
    float SA = 0.f, SV = 0.f;
#pragma unroll
    for (int j = 0; j < 8; ++j) { SA += saL[k][j]; SV += svL[k][j]; }
    int ca = 0;
#pragma unroll
    for (int gg = 0; gg < 4; ++gg) ca += __popcll(planes[gg][k]);
    atomicAdd(&gsa[k * BB + b], SA);
    atomicAdd(&gsv[k * BB + b], SV);
    if (ca) atomicAdd(&gca[k * BB + b], (float)ca);
  }
}

// ---------------------------------------------------------------------------
// Finalize: 1 block over the 2048 (k,b) pairs (logic verified R2-R5).
// ---------------------------------------------------------------------------
__global__ __launch_bounds__(256) void fin_kernel(
    const float* __restrict__ gsa, const float* __restrict__ gsv,
    const float* __restrict__ gca, const int* __restrict__ len,
    float* __restrict__ out) {
  float s = 0.f;
  for (int i = threadIdx.x; i < KK * BB; i += 256) {
    const int b = i & (BB - 1);
    const float ca = gca[i];
    const float cn = (float)len[b] - ca;
    if (ca > 0.f && cn > 0.f) {
      const float sa = gsa[i];
      const float sv = gsv[i];
      const float d = MARGIN_F - (sa / ca - (sv - sa) / cn);
      s += d > 0.f ? d : 0.f;
    }
  }
#pragma unroll
  for (int off = 32; off > 0; off >>= 1) s += __shfl_down(s, off);
  __shared__ float ws4[4];
  if ((threadIdx.x & 63) == 0) ws4[threadIdx.x >> 6] = s;
  __syncthreads();
  if (threadIdx.x == 0) {
    const float S = ws4[0] + ws4[1] + ws4[2] + ws4[3];
    const float ac = S * (1.0f / (float)(KK * BB));
    out[0] = ac;
    out[1] = ac * LAMBDA_F;
  }
}

extern "C" void kernel_launch(void* const* d_in, const int* in_sizes, int n_in,
                              void* d_out, int out_size, void* d_ws, size_t ws_size,
                              hipStream_t stream) {
  const float* pred_orig = (const float*)d_in[0];   // [B,TV] fp32
  const float* pred_int  = (const float*)d_in[1];   // [K,B,TV] fp32
  const int*   idx       = (const int*)d_in[2];     // [K] int32
  const int*   gt        = (const int*)d_in[3];     // [B,TV,TS] int32
  const int*   mv        = (const int*)d_in[4];     // [B,TV] int32
  float* out = (float*)d_out;

  float* gsa = (float*)d_ws;
  float* gsv = gsa + KK * BB;
  float* gca = gsv + KK * BB;
  int*   len = (int*)(gca + KK * BB);

  // zero the accumulator region (ws re-poisoned to 0xAA each call)
  hipMemsetAsync(d_ws, 0, (size_t)(3 * KK * BB) * sizeof(float) + BB * sizeof(int),
                 stream);
  fused_kernel<<<BB * NTILE, 256, 0, stream>>>(
      pred_orig, pred_int, idx, gt, mv, gsa, gsv, gca, len);
  fin_kernel<<<1, 256, 0, stream>>>(gsa, gsv, gca, len, out);
}